// Round 11
// baseline (5962.703 us; speedup 1.0000x reference)
//
#include <hip/hip_runtime.h>
#include <hip/hip_bf16.h>
#include <math.h>

#define VDIM 128
#define HDIM 512
#define BATCH 512
#define RPB 8                  // batch rows per scan block
#define NSCAN 64               // scan blocks (XCDs 0-3, 16 CUs each)
#define NWORK 128              // persistent fnet workers (XCDs 4-7)
#define NT 512
#define NWAVE 8
#define KSPL 8                 // K-split chunks (one per wave)
#define LN_EPS 1e-5f
#define FROWS 32               // fnet rows per tile
#define NGRP 16                // worker row groups
#define SPG 4                  // scan blocks per worker row group (32/8)

// ---------- float4 helpers ----------
__device__ __forceinline__ float4 f4zero() { return make_float4(0.f, 0.f, 0.f, 0.f); }
__device__ __forceinline__ float4 f4add(float4 a, float4 b) {
    return make_float4(a.x + b.x, a.y + b.y, a.z + b.z, a.w + b.w);
}
__device__ __forceinline__ float4 f4fma(float4 a, float s, float4 c) {
    return make_float4(fmaf(a.x, s, c.x), fmaf(a.y, s, c.y),
                       fmaf(a.z, s, c.z), fmaf(a.w, s, c.w));
}
__device__ __forceinline__ float4 f4scale(float4 a, float s) {
    return make_float4(a.x * s, a.y * s, a.z * s, a.w * s);
}
__device__ __forceinline__ float4 f4sub(float4 a, float4 b) {
    return make_float4(a.x - b.x, a.y - b.y, a.z - b.z, a.w - b.w);
}
__device__ __forceinline__ float4 f4sq(float4 a) {
    return make_float4(a.x * a.x, a.y * a.y, a.z * a.z, a.w * a.w);
}
__device__ __forceinline__ float f4get(float4 v, int r) {
    return r == 0 ? v.x : r == 1 ? v.y : r == 2 ? v.z : v.w;
}

struct Params {
    const float *u;
    const float *q_w1, *q_b1, *q_g1, *q_be1;
    const float *q_w2, *q_b2, *q_g2, *q_be2;
    const float *q_w3, *q_b3, *q_g3, *q_be3;
    const float *q_W, *q_bias, *q_marg;
    const float *f_w1, *f_b1, *f_g1, *f_be1;
    const float *f_w2, *f_b2, *f_g2, *f_be2;
    const float *f_w3, *f_b3, *f_g3, *f_be3;
    const float *f_w4, *f_b4, *J;
    const int *top_order, *pa_mask;
    int *wflag;
    float *V_out, *lp, *lf, *score, *vs, *loss;
};

// ---------------- shared memory (union ~106KB -> 1 block/CU) -------------
struct ScanS {
    float4 VT[VDIM][2];        // V^T: [col][rows0-3 | rows4-7]
    float4 VPTlo[VDIM], VPThi[VDIM];   // layer-1 input (linear by col)
    float4 Alo[HDIM], Ahi[HDIM];       // activations ping (st layout)
    float4 Blo[HDIM], Bhi[HDIM];       // activations pong
    float4 part[4][KSPL][128]; // [j][chunk][colblock]  64KB (two-phase reuse)
    float4 red4x[NWAVE][4];
    float4 red2x[NWAVE][2];
    int ord[VDIM];
    int emptyb[VDIM];
};
struct WorkS {
    float Vt[VDIM * FROWS];    // 16KB [k][32]
    float A[HDIM * FROWS];     // 64KB [c][32]
    int ord[VDIM], invp[VDIM];
    float4 redA[NWAVE], redB[NWAVE];
};
union SMem { ScanS s; WorkS w; };

// st layout: column c's value stored at index st(c); st(myc(tid)) == tid
__device__ __forceinline__ int stpos(int c) {
    return 256 * (c >> 8) + 64 * (c & 3) + ((c & 255) >> 2);
}

// ---- block-wide 2xf4 allreduce, ONE sync --------------------------------
__device__ __forceinline__ void allreduce2_1s(float4 &a, float4 &b,
                                              float4 (*red)[2], int tid) {
#pragma unroll
    for (int off = 1; off < 64; off <<= 1) {
        a.x += __shfl_xor(a.x, off, 64); a.y += __shfl_xor(a.y, off, 64);
        a.z += __shfl_xor(a.z, off, 64); a.w += __shfl_xor(a.w, off, 64);
        b.x += __shfl_xor(b.x, off, 64); b.y += __shfl_xor(b.y, off, 64);
        b.z += __shfl_xor(b.z, off, 64); b.w += __shfl_xor(b.w, off, 64);
    }
    if ((tid & 63) == 0) { red[tid >> 6][0] = a; red[tid >> 6][1] = b; }
    __syncthreads();
    float4 sa = red[0][0], sb = red[0][1];
#pragma unroll
    for (int w = 1; w < NWAVE; ++w) { sa = f4add(sa, red[w][0]); sb = f4add(sb, red[w][1]); }
    a = sa; b = sb;   // no trailing sync (next red write >=1 sync away)
}

// ---- block-wide 4xf4 allreduce (fused LN stats for 8 rows), ONE sync ----
__device__ __forceinline__ void allreduce4_1s(float4 &a, float4 &b,
                                              float4 &c, float4 &d,
                                              float4 (*red)[4], int tid) {
#pragma unroll
    for (int off = 1; off < 64; off <<= 1) {
        a.x += __shfl_xor(a.x, off, 64); a.y += __shfl_xor(a.y, off, 64);
        a.z += __shfl_xor(a.z, off, 64); a.w += __shfl_xor(a.w, off, 64);
        b.x += __shfl_xor(b.x, off, 64); b.y += __shfl_xor(b.y, off, 64);
        b.z += __shfl_xor(b.z, off, 64); b.w += __shfl_xor(b.w, off, 64);
        c.x += __shfl_xor(c.x, off, 64); c.y += __shfl_xor(c.y, off, 64);
        c.z += __shfl_xor(c.z, off, 64); c.w += __shfl_xor(c.w, off, 64);
        d.x += __shfl_xor(d.x, off, 64); d.y += __shfl_xor(d.y, off, 64);
        d.z += __shfl_xor(d.z, off, 64); d.w += __shfl_xor(d.w, off, 64);
    }
    int w = tid >> 6;
    if ((tid & 63) == 0) { red[w][0] = a; red[w][1] = b; red[w][2] = c; red[w][3] = d; }
    __syncthreads();
    float4 sa = red[0][0], sb = red[0][1], sc = red[0][2], sd = red[0][3];
#pragma unroll
    for (int q = 1; q < NWAVE; ++q) {
        sa = f4add(sa, red[q][0]); sb = f4add(sb, red[q][1]);
        sc = f4add(sc, red[q][2]); sd = f4add(sd, red[q][3]);
    }
    a = sa; b = sb; c = sc; d = sd;
}

__device__ __forceinline__ float block_reduce1(float v, float *red, int tid) {
#pragma unroll
    for (int off = 1; off < 64; off <<= 1) v += __shfl_xor(v, off, 64);
    if ((tid & 63) == 0) red[tid >> 6] = v;
    __syncthreads();
    float s = 0.f;
#pragma unroll
    for (int w = 0; w < NWAVE; ++w) s += red[w];
    __syncthreads();
    return s;
}

__device__ __forceinline__ void redpair(float4 &a, float4 &b,
                                        float4 *redA, float4 *redB, int tid) {
#pragma unroll
    for (int off = 1; off < 64; off <<= 1) {
        a.x += __shfl_xor(a.x, off, 64); a.y += __shfl_xor(a.y, off, 64);
        a.z += __shfl_xor(a.z, off, 64); a.w += __shfl_xor(a.w, off, 64);
        b.x += __shfl_xor(b.x, off, 64); b.y += __shfl_xor(b.y, off, 64);
        b.z += __shfl_xor(b.z, off, 64); b.w += __shfl_xor(b.w, off, 64);
    }
    int w = tid >> 6;
    if ((tid & 63) == 0) { redA[w] = a; redB[w] = b; }
    __syncthreads();
    int p = w ^ 1;
    a = f4add(redA[w], redA[p]);
    b = f4add(redB[w], redB[p]);
    __syncthreads();
}

// -------- scan GEMV+LN: 8 rows, CPT=8, 8-way K-split, two-phase combine --
// Thread (ks=tid>>6, cq=tid&63) streams K-chunk ks for col-blocks {cq,64+cq}.
// Combine/LN: thread owns col myc = 4*(tid&63) + ((tid>>6)&3) + 256*(tid>>8).
// Returns h (8 rows of col myc) in registers; writes st-layout out if WOUT.
template <int K, bool LIN, bool WOUT>
__device__ __forceinline__ void gemv8_ln(const float4 *__restrict__ inLo,
                                         const float4 *__restrict__ inHi,
                                         const float *__restrict__ W,
                                         const float *__restrict__ bias,
                                         const float *__restrict__ gam,
                                         const float *__restrict__ bet,
                                         float4 *__restrict__ outLo,
                                         float4 *__restrict__ outHi,
                                         ScanS &S, int tid, int ks, int cq,
                                         int myc, int myj, int mycb,
                                         float4 &hLo, float4 &hHi) {
    constexpr int kc = K / KSPL;
    const float4 *WA = (const float4 *)W + cq;
    const float4 *WB = WA + 64;
    float4 aAl0 = f4zero(), aAl1 = f4zero(), aAl2 = f4zero(), aAl3 = f4zero();
    float4 aAh0 = f4zero(), aAh1 = f4zero(), aAh2 = f4zero(), aAh3 = f4zero();
    float4 aBl0 = f4zero(), aBl1 = f4zero(), aBl2 = f4zero(), aBl3 = f4zero();
    float4 aBh0 = f4zero(), aBh1 = f4zero(), aBh2 = f4zero(), aBh3 = f4zero();
#pragma unroll 2
    for (int q = 0; q < kc; ++q) {
        const int k = ks * kc + q;
        const int pos = LIN ? k : stpos(k);
        float4 alo = inLo[pos];            // LDS b128, wave-uniform broadcast
        float4 ahi = inHi[pos];
        float4 wa = WA[(size_t)k * (HDIM / 4)];   // 1KB/wave coalesced
        float4 wb = WB[(size_t)k * (HDIM / 4)];
        aAl0 = f4fma(alo, wa.x, aAl0); aAh0 = f4fma(ahi, wa.x, aAh0);
        aAl1 = f4fma(alo, wa.y, aAl1); aAh1 = f4fma(ahi, wa.y, aAh1);
        aAl2 = f4fma(alo, wa.z, aAl2); aAh2 = f4fma(ahi, wa.z, aAh2);
        aAl3 = f4fma(alo, wa.w, aAl3); aAh3 = f4fma(ahi, wa.w, aAh3);
        aBl0 = f4fma(alo, wb.x, aBl0); aBh0 = f4fma(ahi, wb.x, aBh0);
        aBl1 = f4fma(alo, wb.y, aBl1); aBh1 = f4fma(ahi, wb.y, aBh1);
        aBl2 = f4fma(alo, wb.z, aBl2); aBh2 = f4fma(ahi, wb.z, aBh2);
        aBl3 = f4fma(alo, wb.w, aBl3); aBh3 = f4fma(ahi, wb.w, aBh3);
    }
    // phase LO: partials for rows 0-3 (conflict-free: lane stride 16B per j)
    S.part[0][ks][cq] = aAl0; S.part[1][ks][cq] = aAl1;
    S.part[2][ks][cq] = aAl2; S.part[3][ks][cq] = aAl3;
    S.part[0][ks][64 + cq] = aBl0; S.part[1][ks][64 + cq] = aBl1;
    S.part[2][ks][64 + cq] = aBl2; S.part[3][ks][64 + cq] = aBl3;
    __syncthreads();                                   // S1
    float4 zlo = S.part[myj][0][mycb];
#pragma unroll
    for (int s = 1; s < KSPL; ++s) zlo = f4add(zlo, S.part[myj][s][mycb]);
    __syncthreads();                                   // S2 (LO reads done)
    // phase HI: rows 4-7 reuse the same buffer
    S.part[0][ks][cq] = aAh0; S.part[1][ks][cq] = aAh1;
    S.part[2][ks][cq] = aAh2; S.part[3][ks][cq] = aAh3;
    S.part[0][ks][64 + cq] = aBh0; S.part[1][ks][64 + cq] = aBh1;
    S.part[2][ks][64 + cq] = aBh2; S.part[3][ks][64 + cq] = aBh3;
    __syncthreads();                                   // S3
    float4 zhi = S.part[myj][0][mycb];
#pragma unroll
    for (int s = 1; s < KSPL; ++s) zhi = f4add(zhi, S.part[myj][s][mycb]);

    float bc = bias[myc];
    zlo.x += bc; zlo.y += bc; zlo.z += bc; zlo.w += bc;
    zhi.x += bc; zhi.y += bc; zhi.z += bc; zhi.w += bc;

    // fused LN stats for 8 rows: one allreduce of (sum_lo, sum_hi, sq_lo, sq_hi)
    const float inv = 1.f / (float)HDIM;
    float4 s1l = zlo, s1h = zhi, s2l = f4sq(zlo), s2h = f4sq(zhi);
    allreduce4_1s(s1l, s1h, s2l, s2h, S.red4x, tid);   // S4
    float4 ml = f4scale(s1l, inv), mh = f4scale(s1h, inv);
    float4 e2l = f4scale(s2l, inv), e2h = f4scale(s2h, inv);
    float4 vl = make_float4(fmaxf(e2l.x - ml.x * ml.x, 0.f), fmaxf(e2l.y - ml.y * ml.y, 0.f),
                            fmaxf(e2l.z - ml.z * ml.z, 0.f), fmaxf(e2l.w - ml.w * ml.w, 0.f));
    float4 vh = make_float4(fmaxf(e2h.x - mh.x * mh.x, 0.f), fmaxf(e2h.y - mh.y * mh.y, 0.f),
                            fmaxf(e2h.z - mh.z * mh.z, 0.f), fmaxf(e2h.w - mh.w * mh.w, 0.f));
    float4 rl, rh;
    rl.x = 1.f / sqrtf(vl.x + LN_EPS); rl.y = 1.f / sqrtf(vl.y + LN_EPS);
    rl.z = 1.f / sqrtf(vl.z + LN_EPS); rl.w = 1.f / sqrtf(vl.w + LN_EPS);
    rh.x = 1.f / sqrtf(vh.x + LN_EPS); rh.y = 1.f / sqrtf(vh.y + LN_EPS);
    rh.z = 1.f / sqrtf(vh.z + LN_EPS); rh.w = 1.f / sqrtf(vh.w + LN_EPS);
    float4 dl = f4sub(zlo, ml), dh = f4sub(zhi, mh);
    float gc = gam[myc], ec = bet[myc];
    hLo.x = fmaxf(fmaf(dl.x * rl.x, gc, ec), 0.f);
    hLo.y = fmaxf(fmaf(dl.y * rl.y, gc, ec), 0.f);
    hLo.z = fmaxf(fmaf(dl.z * rl.z, gc, ec), 0.f);
    hLo.w = fmaxf(fmaf(dl.w * rl.w, gc, ec), 0.f);
    hHi.x = fmaxf(fmaf(dh.x * rh.x, gc, ec), 0.f);
    hHi.y = fmaxf(fmaf(dh.y * rh.y, gc, ec), 0.f);
    hHi.z = fmaxf(fmaf(dh.z * rh.z, gc, ec), 0.f);
    hHi.w = fmaxf(fmaf(dh.w * rh.w, gc, ec), 0.f);
    if (WOUT) {
        outLo[tid] = hLo;              // st-layout: position tid == st(myc)
        outHi[tid] = hHi;
        __syncthreads();               // S5
    }
}

// ---------------- scan role: qtrunk + sampling, 8 rows -------------------
__device__ void scan_role(const Params &P, int bid, ScanS &S) {
    const int tid = threadIdx.x;
    const int ks = tid >> 6;
    const int cq = tid & 63;
    const int myc = 4 * (tid & 63) + ((tid >> 6) & 3) + 256 * (tid >> 8);
    const int myj = (tid >> 6) & 3;
    const int mycb = (tid & 63) + 64 * (tid >> 8);
    const int row0 = bid * RPB;

    if (tid < VDIM) {
        S.VT[tid][0] = f4zero(); S.VT[tid][1] = f4zero();
        S.ord[tid] = P.top_order[tid];
    }
    __syncthreads();
    if (tid < VDIM) {
        int nd = S.ord[tid];
        int mm = 0;
        for (int jj = 0; jj < tid; ++jj) mm |= P.pa_mask[nd * VDIM + S.ord[jj]];
        S.emptyb[tid] = (mm == 0);
        S.VPTlo[tid] = f4zero();       // V=0 -> V_pa=0 for step 0
        S.VPThi[tid] = f4zero();
    }
    __syncthreads();

    float4 hLo, hHi;
    for (int i = 0; i < VDIM; ++i) {
        const int node = S.ord[i];

        gemv8_ln<VDIM, true, true>(S.VPTlo, S.VPThi, P.q_w1, P.q_b1, P.q_g1, P.q_be1,
                                   S.Alo, S.Ahi, S, tid, ks, cq, myc, myj, mycb, hLo, hHi);
        gemv8_ln<HDIM, false, true>(S.Alo, S.Ahi, P.q_w2, P.q_b2, P.q_g2, P.q_be2,
                                    S.Blo, S.Bhi, S, tid, ks, cq, myc, myj, mycb, hLo, hHi);
        gemv8_ln<HDIM, false, false>(S.Blo, S.Bhi, P.q_w3, P.q_b3, P.q_g3, P.q_be3,
                                     nullptr, nullptr, S, tid, ks, cq, myc, myj, mycb, hLo, hHi);

        // head directly from registers: x[r] = sum_c h3[r][c]*q_W[node][c]
        float wq = P.q_W[(size_t)node * HDIM + myc];
        float4 xl = f4scale(hLo, wq), xh = f4scale(hHi, wq);
        allreduce2_1s(xl, xh, S.red2x, tid);           // head sync

        // merged sample + VPT(i+1): one sync
        {
            const bool empty = (S.emptyb[i] != 0);
            const float qb = P.q_bias[node];
            const float mg = P.q_marg[node];
            float4 pl, ph;
            pl.x = 1.f / (1.f + expf(-(empty ? mg : xl.x + qb)));
            pl.y = 1.f / (1.f + expf(-(empty ? mg : xl.y + qb)));
            pl.z = 1.f / (1.f + expf(-(empty ? mg : xl.z + qb)));
            pl.w = 1.f / (1.f + expf(-(empty ? mg : xl.w + qb)));
            ph.x = 1.f / (1.f + expf(-(empty ? mg : xh.x + qb)));
            ph.y = 1.f / (1.f + expf(-(empty ? mg : xh.y + qb)));
            ph.z = 1.f / (1.f + expf(-(empty ? mg : xh.z + qb)));
            ph.w = 1.f / (1.f + expf(-(empty ? mg : xh.w + qb)));
            const float4 *up = (const float4 *)(P.u + (size_t)i * BATCH + row0);
            float4 ul = up[0], uh = up[1];
            float4 nl = make_float4(ul.x < pl.x ? 1.f : -1.f, ul.y < pl.y ? 1.f : -1.f,
                                    ul.z < pl.z ? 1.f : -1.f, ul.w < pl.w ? 1.f : -1.f);
            float4 nh = make_float4(uh.x < ph.x ? 1.f : -1.f, uh.y < ph.y ? 1.f : -1.f,
                                    uh.z < ph.z ? 1.f : -1.f, uh.w < ph.w ? 1.f : -1.f);
            if (tid < VDIM) {
                float mk = 0.f;
                if (i + 1 < VDIM) {
                    int nodeN = S.ord[i + 1];
                    mk = (float)P.pa_mask[nodeN * VDIM + tid];
                }
                float4 vkl = S.VT[tid][0], vkh = S.VT[tid][1];
                if (tid == node) {
                    vkl = nl; vkh = nh;
                    S.VT[tid][0] = nl; S.VT[tid][1] = nh;
                }
                S.VPTlo[tid] = f4scale(vkl, mk);
                S.VPThi[tid] = f4scale(vkh, mk);
            }
            if (tid < RPB) {
                float pr = (tid < 4) ? f4get(pl, tid) : f4get(ph, tid - 4);
                float vr = (tid < 4) ? f4get(nl, tid) : f4get(nh, tid - 4);
                __hip_atomic_store(&P.vs[(size_t)i * BATCH + row0 + tid], vr,
                                   __ATOMIC_RELAXED, __HIP_MEMORY_SCOPE_AGENT);
                P.lp[(size_t)i * BATCH + row0 + tid] =
                    (vr > 0.f) ? logf(pr) : log1pf(-pr);
            }
            __syncthreads();           // sample sync
            if (tid == 0)
                __hip_atomic_store(P.wflag + bid, i + 1,
                                   __ATOMIC_RELEASE, __HIP_MEMORY_SCOPE_AGENT);
        }
    }

    // terminal score: V . J . V per row (8 rows)
    float4 il = f4zero(), ih = f4zero();
    if (tid < VDIM) {
#pragma unroll 4
        for (int ii = 0; ii < VDIM; ++ii) {
            float jv = P.J[(size_t)ii * VDIM + tid];
            il = f4fma(S.VT[ii][0], jv, il);
            ih = f4fma(S.VT[ii][1], jv, ih);
        }
        float4 vl = S.VT[tid][0], vh = S.VT[tid][1];
        il = make_float4(il.x * vl.x, il.y * vl.y, il.z * vl.z, il.w * vl.w);
        ih = make_float4(ih.x * vh.x, ih.y * vh.y, ih.z * vh.z, ih.w * vh.w);
    }
    allreduce2_1s(il, ih, S.red2x, tid);
    if (tid < RPB)
        P.score[row0 + tid] = (tid < 4) ? f4get(il, tid) : f4get(ih, tid - 4);
    if (tid < VDIM) {
        float4 vl = S.VT[tid][0], vh = S.VT[tid][1];
        P.V_out[(size_t)(row0 + 0) * VDIM + tid] = vl.x;
        P.V_out[(size_t)(row0 + 1) * VDIM + tid] = vl.y;
        P.V_out[(size_t)(row0 + 2) * VDIM + tid] = vl.z;
        P.V_out[(size_t)(row0 + 3) * VDIM + tid] = vl.w;
        P.V_out[(size_t)(row0 + 4) * VDIM + tid] = vh.x;
        P.V_out[(size_t)(row0 + 5) * VDIM + tid] = vh.y;
        P.V_out[(size_t)(row0 + 6) * VDIM + tid] = vh.z;
        P.V_out[(size_t)(row0 + 7) * VDIM + tid] = vh.w;
    }
}

// ---------------- fnet layer, 512 threads, 32-row tile (unchanged) -------
template <int K>
__device__ __forceinline__ void flayer512(const float *__restrict__ in,
                                          const float *__restrict__ W,
                                          const float *__restrict__ bias,
                                          const float *__restrict__ gam,
                                          const float *__restrict__ bet,
                                          float *__restrict__ out,
                                          float4 *redA, float4 *redB, int tid) {
    const int rh = tid >> 7;
    const int cq = tid & 127;
    const float4 *Wv = (const float4 *)W + cq;
    float4 accA[4], accB[4];
#pragma unroll
    for (int j = 0; j < 4; ++j) { accA[j] = f4zero(); accB[j] = f4zero(); }
#pragma unroll 4
    for (int k = 0; k < K; ++k) {
        float4 w = Wv[(size_t)k * (HDIM / 4)];
        const float *ip = in + k * FROWS + 8 * rh;
        float4 vA = *(const float4 *)ip;
        float4 vB = *(const float4 *)(ip + 4);
        accA[0] = f4fma(vA, w.x, accA[0]); accB[0] = f4fma(vB, w.x, accB[0]);
        accA[1] = f4fma(vA, w.y, accA[1]); accB[1] = f4fma(vB, w.y, accB[1]);
        accA[2] = f4fma(vA, w.z, accA[2]); accB[2] = f4fma(vB, w.z, accB[2]);
        accA[3] = f4fma(vA, w.w, accA[3]); accB[3] = f4fma(vB, w.w, accB[3]);
    }
    float4 b4 = ((const float4 *)bias)[cq];
    float bb[4] = {b4.x, b4.y, b4.z, b4.w};
#pragma unroll
    for (int j = 0; j < 4; ++j) {
        accA[j].x += bb[j]; accA[j].y += bb[j]; accA[j].z += bb[j]; accA[j].w += bb[j];
        accB[j].x += bb[j]; accB[j].y += bb[j]; accB[j].z += bb[j]; accB[j].w += bb[j];
    }
    const float inv = 1.f / (float)HDIM;
    float4 sA = f4add(f4add(accA[0], accA[1]), f4add(accA[2], accA[3]));
    float4 sB = f4add(f4add(accB[0], accB[1]), f4add(accB[2], accB[3]));
    redpair(sA, sB, redA, redB, tid);
    float4 mA = f4scale(sA, inv), mB = f4scale(sB, inv);
    float4 dA[4], dB[4];
    float4 qA = f4zero(), qB = f4zero();
#pragma unroll
    for (int j = 0; j < 4; ++j) {
        dA[j] = f4sub(accA[j], mA);
        dB[j] = f4sub(accB[j], mB);
        qA.x += dA[j].x * dA[j].x; qA.y += dA[j].y * dA[j].y;
        qA.z += dA[j].z * dA[j].z; qA.w += dA[j].w * dA[j].w;
        qB.x += dB[j].x * dB[j].x; qB.y += dB[j].y * dB[j].y;
        qB.z += dB[j].z * dB[j].z; qB.w += dB[j].w * dB[j].w;
    }
    redpair(qA, qB, redA, redB, tid);
    float4 rsA, rsB;
    rsA.x = 1.f / sqrtf(qA.x * inv + LN_EPS); rsA.y = 1.f / sqrtf(qA.y * inv + LN_EPS);
    rsA.z = 1.f / sqrtf(qA.z * inv + LN_EPS); rsA.w = 1.f / sqrtf(qA.w * inv + LN_EPS);
    rsB.x = 1.f / sqrtf(qB.x * inv + LN_EPS); rsB.y = 1.f / sqrtf(qB.y * inv + LN_EPS);
    rsB.z = 1.f / sqrtf(qB.z * inv + LN_EPS); rsB.w = 1.f / sqrtf(qB.w * inv + LN_EPS);
    float4 g4 = ((const float4 *)gam)[cq];
    float4 e4 = ((const float4 *)bet)[cq];
    float gg[4] = {g4.x, g4.y, g4.z, g4.w};
    float ee[4] = {e4.x, e4.y, e4.z, e4.w};
#pragma unroll
    for (int j = 0; j < 4; ++j) {
        float4 hA, hB;
        hA.x = fmaxf(fmaf(dA[j].x * rsA.x, gg[j], ee[j]), 0.f);
        hA.y = fmaxf(fmaf(dA[j].y * rsA.y, gg[j], ee[j]), 0.f);
        hA.z = fmaxf(fmaf(dA[j].z * rsA.z, gg[j], ee[j]), 0.f);
        hA.w = fmaxf(fmaf(dA[j].w * rsA.w, gg[j], ee[j]), 0.f);
        hB.x = fmaxf(fmaf(dB[j].x * rsB.x, gg[j], ee[j]), 0.f);
        hB.y = fmaxf(fmaf(dB[j].y * rsB.y, gg[j], ee[j]), 0.f);
        hB.z = fmaxf(fmaf(dB[j].z * rsB.z, gg[j], ee[j]), 0.f);
        hB.w = fmaxf(fmaf(dB[j].w * rsB.w, gg[j], ee[j]), 0.f);
        float *op = out + (4 * cq + j) * FROWS + 8 * rh;
        *(float4 *)op = hA;
        *(float4 *)(op + 4) = hB;
    }
    __syncthreads();
}

// ---------------- worker role --------------------------------------------
__device__ void worker_role(const Params &P, int wid, WorkS &S) {
    const int tid = threadIdx.x;
    if (tid < VDIM) S.ord[tid] = P.top_order[tid];
    __syncthreads();
    if (tid < VDIM) S.invp[S.ord[tid]] = tid;
    __syncthreads();
    const int g = wid & (NGRP - 1);
    const int r0 = g * FROWS;

    for (int tile = wid; tile < VDIM * NGRP; tile += NWORK) {
        const int t = tile >> 4;
        if (t == VDIM - 1) continue;
        if (tid < SPG) {
            const int need = t + 1;
            while (__hip_atomic_load(P.wflag + (SPG * g + tid),
                                     __ATOMIC_RELAXED,
                                     __HIP_MEMORY_SCOPE_AGENT) < need)
                __builtin_amdgcn_s_sleep(4);
        }
        __syncthreads();
        for (int idx = tid; idx < VDIM * FROWS; idx += NT) {
            int k = idx >> 5, rr = idx & (FROWS - 1);
            int s = S.invp[k];
            S.Vt[idx] = (s <= t)
                ? __hip_atomic_load(&P.vs[(size_t)s * BATCH + r0 + rr],
                                    __ATOMIC_RELAXED, __HIP_MEMORY_SCOPE_AGENT)
                : 0.f;
        }
        __syncthreads();

        flayer512<VDIM>(S.Vt, P.f_w1, P.f_b1, P.f_g1, P.f_be1, S.A, S.redA, S.redB, tid);
        flayer512<HDIM>(S.A, P.f_w2, P.f_b2, P.f_g2, P.f_be2, S.A, S.redA, S.redB, tid);
        flayer512<HDIM>(S.A, P.f_w3, P.f_b3, P.f_g3, P.f_be3, S.A, S.redA, S.redB, tid);

        const int rh = tid >> 7, cq = tid & 127;
        float4 w4 = ((const float4 *)P.f_w4)[cq];
        float ww[4] = {w4.x, w4.y, w4.z, w4.w};
        float4 sA = f4zero(), sB = f4zero();
#pragma unroll
        for (int j = 0; j < 4; ++j) {
            const float *ap2 = S.A + (4 * cq + j) * FROWS + 8 * rh;
            float4 vA = *(const float4 *)ap2;
            float4 vB = *(const float4 *)(ap2 + 4);
            sA = f4fma(vA, ww[j], sA);
            sB = f4fma(vB, ww[j], sB);
        }
        redpair(sA, sB, S.redA, S.redB, tid);
        if (cq == 0) {
            float b4v = P.f_b4[0];
            float *dst = P.lf + (size_t)t * BATCH + r0 + 8 * rh;
            dst[0] = sA.x + b4v; dst[1] = sA.y + b4v;
            dst[2] = sA.z + b4v; dst[3] = sA.w + b4v;
            dst[4] = sB.x + b4v; dst[5] = sB.y + b4v;
            dst[6] = sB.z + b4v; dst[7] = sB.w + b4v;
        }
        __syncthreads();
    }
}

// 64 scan blocks spread over XCDs 0-3 (16 CUs/XCD -> halved same-line L2
// pressure); 64 sibling blocks on XCDs 0-3 exit immediately; 128 workers on
// XCDs 4-7. Grid=256 at 1 block/CU => co-residency => deadlock-free.
__global__ __launch_bounds__(NT) void gfn_main(Params P) {
    __shared__ SMem sm;
    const int xcd = blockIdx.x & 7;
    const int grp = blockIdx.x >> 3;       // 0..31
    if (xcd < 4) {
        const int sid = grp * 4 + xcd;
        if (sid < NSCAN) scan_role(P, sid, sm.s);
        // else: idle-exit (keeps q-weight L2s clean)
    } else {
        worker_role(P, grp * 4 + (xcd - 4), sm.w);
    }
}

// ---------------- loss ----------------
__global__ __launch_bounds__(NT) void gfn_loss(Params P) {
    __shared__ float H1[HDIM], H2[HDIM];
    __shared__ float red1[NWAVE];
    const int tid = threadIdx.x;
    const float inv = 1.f / (float)HDIM;

    float z = P.f_b1[tid];
    float m = block_reduce1(z, red1, tid) * inv;
    float d = z - m;
    float var = block_reduce1(d * d, red1, tid) * inv;
    float h = fmaxf(fmaf(d * (1.f / sqrtf(var + LN_EPS)), P.f_g1[tid], P.f_be1[tid]), 0.f);
    H1[tid] = h;
    __syncthreads();

    float acc = 0.f;
    for (int k = 0; k < HDIM; ++k) acc = fmaf(H1[k], P.f_w2[(size_t)k * HDIM + tid], acc);
    z = acc + P.f_b2[tid];
    m = block_reduce1(z, red1, tid) * inv;
    d = z - m;
    var = block_reduce1(d * d, red1, tid) * inv;
    h = fmaxf(fmaf(d * (1.f / sqrtf(var + LN_EPS)), P.f_g2[tid], P.f_be2[tid]), 0.f);
    H2[tid] = h;
    __syncthreads();

    acc = 0.f;
    for (int k = 0; k < HDIM; ++k) acc = fmaf(H2[k], P.f_w3[(size_t)k * HDIM + tid], acc);
    z = acc + P.f_b3[tid];
    m = block_reduce1(z, red1, tid) * inv;
    d = z - m;
    var = block_reduce1(d * d, red1, tid) * inv;
    h = fmaxf(fmaf(d * (1.f / sqrtf(var + LN_EPS)), P.f_g3[tid], P.f_be3[tid]), 0.f);
    float F0 = block_reduce1(h * P.f_w4[tid], red1, tid) + P.f_b4[0];

    const int b = tid;
    float lfp = F0;
    float s = 0.f;
    for (int t = 0; t < VDIM; ++t) {
        float lp = P.lp[(size_t)t * BATCH + b];
        float lfn = (t == VDIM - 1) ? P.score[b] : P.lf[(size_t)t * BATCH + b];
        float dd = lfp + lp - lfn;
        s = fmaf(dd, dd, s);
        lfp = lfn;
    }
    s *= (1.f / (float)VDIM);
    float total = block_reduce1(s, red1, tid) * (1.f / (float)BATCH);
    if (tid == 0) P.loss[0] = total;
}

extern "C" void kernel_launch(void *const *d_in, const int *in_sizes, int n_in,
                              void *d_out, int out_size, void *d_ws, size_t ws_size,
                              hipStream_t stream) {
    Params P;
    P.u     = (const float *)d_in[0];
    P.q_w1  = (const float *)d_in[1];
    P.q_b1  = (const float *)d_in[2];
    P.q_g1  = (const float *)d_in[3];
    P.q_be1 = (const float *)d_in[4];
    P.q_w2  = (const float *)d_in[5];
    P.q_b2  = (const float *)d_in[6];
    P.q_g2  = (const float *)d_in[7];
    P.q_be2 = (const float *)d_in[8];
    P.q_w3  = (const float *)d_in[9];
    P.q_b3  = (const float *)d_in[10];
    P.q_g3  = (const float *)d_in[11];
    P.q_be3 = (const float *)d_in[12];
    P.q_W   = (const float *)d_in[13];
    P.q_bias= (const float *)d_in[14];
    P.q_marg= (const float *)d_in[15];
    P.f_w1  = (const float *)d_in[16];
    P.f_b1  = (const float *)d_in[17];
    P.f_g1  = (const float *)d_in[18];
    P.f_be1 = (const float *)d_in[19];
    P.f_w2  = (const float *)d_in[20];
    P.f_b2  = (const float *)d_in[21];
    P.f_g2  = (const float *)d_in[22];
    P.f_be2 = (const float *)d_in[23];
    P.f_w3  = (const float *)d_in[24];
    P.f_b3  = (const float *)d_in[25];
    P.f_g3  = (const float *)d_in[26];
    P.f_be3 = (const float *)d_in[27];
    P.f_w4  = (const float *)d_in[28];
    P.f_b4  = (const float *)d_in[29];
    P.J     = (const float *)d_in[30];
    P.top_order = (const int *)d_in[31];
    P.pa_mask   = (const int *)d_in[32];

    float *ws = (float *)d_ws;
    P.V_out = (float *)d_out;
    P.loss  = (float *)d_out + (size_t)BATCH * VDIM;
    P.lp    = ws;                                       // [128][512]
    P.lf    = ws + (size_t)VDIM * BATCH;                // [128][512]
    P.score = ws + 2 * (size_t)VDIM * BATCH;            // [512]
    P.vs    = ws + 2 * (size_t)VDIM * BATCH + BATCH;    // [128][512]
    P.wflag = (int *)(ws + 3 * (size_t)VDIM * BATCH + BATCH);  // [64]

    hipMemsetAsync(P.wflag, 0, NSCAN * sizeof(int), stream);
    gfn_main<<<dim3(256), dim3(NT), 0, stream>>>(P);
    gfn_loss<<<dim3(1), dim3(NT), 0, stream>>>(P);
}

// Round 12
// 5048.220 us; speedup vs baseline: 1.1811x; 1.1811x over previous
//
#include <hip/hip_runtime.h>
#include <hip/hip_bf16.h>
#include <math.h>

#define VDIM 128
#define HDIM 512
#define BATCH 512
#define RPB 4                  // batch rows per scan block
#define NBLK (BATCH / RPB)     // 128 scan blocks
#define NWORK 128              // persistent fnet worker blocks
#define NT 512
#define NWAVE 8
#define LN_EPS 1e-5f
#define FROWS 32               // fnet rows per tile
#define NGRP 16                // worker row groups (32 rows)
#define SBPG 8                 // scan blocks per worker row group

// ---------- float4 helpers ----------
__device__ __forceinline__ float4 f4zero() { return make_float4(0.f, 0.f, 0.f, 0.f); }
__device__ __forceinline__ float4 f4add(float4 a, float4 b) {
    return make_float4(a.x + b.x, a.y + b.y, a.z + b.z, a.w + b.w);
}
__device__ __forceinline__ float4 f4fma(float4 a, float s, float4 c) {
    return make_float4(fmaf(a.x, s, c.x), fmaf(a.y, s, c.y),
                       fmaf(a.z, s, c.z), fmaf(a.w, s, c.w));
}
__device__ __forceinline__ float4 f4scale(float4 a, float s) {
    return make_float4(a.x * s, a.y * s, a.z * s, a.w * s);
}
__device__ __forceinline__ float4 f4sub(float4 a, float4 b) {
    return make_float4(a.x - b.x, a.y - b.y, a.z - b.z, a.w - b.w);
}
__device__ __forceinline__ float f4get(float4 v, int r) {
    return r == 0 ? v.x : r == 1 ? v.y : r == 2 ? v.z : v.w;
}

// non-temporal streaming load (bypass/stream L1) for weight streams:
// values identical to a normal load; only cache allocation policy changes.
typedef float vfloat4 __attribute__((ext_vector_type(4)));
__device__ __forceinline__ float4 ntload4(const float4 *p) {
    vfloat4 v = __builtin_nontemporal_load((const vfloat4 *)p);
    return make_float4(v.x, v.y, v.z, v.w);
}

struct Params {
    const float *u;
    const float *q_w1, *q_b1, *q_g1, *q_be1;
    const float *q_w2, *q_b2, *q_g2, *q_be2;
    const float *q_w3, *q_b3, *q_g3, *q_be3;
    const float *q_W, *q_bias, *q_marg;
    const float *f_w1, *f_b1, *f_g1, *f_be1;
    const float *f_w2, *f_b2, *f_g2, *f_be2;
    const float *f_w3, *f_b3, *f_g3, *f_be3;
    const float *f_w4, *f_b4, *J;
    const int *top_order, *pa_mask;
    int *wflag;
    float *V_out, *lp, *lf, *score, *vs, *loss;
};

// ---------------- shared-memory roles (union -> ~82KB -> 1 block/CU) -----
struct ScanS {
    float4 VT[VDIM];           // V^T: [col] -> 4 rows
    float4 VPT[VDIM];          // permuted layer-1 input
    float4 ATa[HDIM];          // permuted activations st(c)=(c&3)*(K/4)+(c>>2)
    float4 ATb[HDIM];
    float4 part[4][4][128];    // [j][ks][cb]  32KB
    float4 red2[NWAVE][2];     // fused-stat allreduce
    float4 redH[NWAVE];        // head / score allreduce
    int ord[VDIM];
    int emptyb[VDIM];          // precomputed empty-parent flags per step
};
struct WorkS {
    float Vt[VDIM * FROWS];    // 16KB [k][32]
    float A[HDIM * FROWS];     // 64KB [c][32]
    int ord[VDIM], invp[VDIM];
    float4 redA[NWAVE], redB[NWAVE];
};
union SMem { ScanS s; WorkS w; };

// ---- block-wide f4 allreduce, ONE sync ---------------------------------
__device__ __forceinline__ float4 allreduce4_1s(float4 v, float4 *red, int tid) {
#pragma unroll
    for (int off = 1; off < 64; off <<= 1) {
        v.x += __shfl_xor(v.x, off, 64);
        v.y += __shfl_xor(v.y, off, 64);
        v.z += __shfl_xor(v.z, off, 64);
        v.w += __shfl_xor(v.w, off, 64);
    }
    if ((tid & 63) == 0) red[tid >> 6] = v;
    __syncthreads();
    float4 s = red[0];
#pragma unroll
    for (int w = 1; w < NWAVE; ++w) s = f4add(s, red[w]);
    return s;   // no trailing sync
}

// ---- block-wide 2xf4 allreduce (fused mean/meansq), ONE sync -----------
__device__ __forceinline__ void allreduce2_1s(float4 &a, float4 &b,
                                              float4 (*red)[2], int tid) {
#pragma unroll
    for (int off = 1; off < 64; off <<= 1) {
        a.x += __shfl_xor(a.x, off, 64); a.y += __shfl_xor(a.y, off, 64);
        a.z += __shfl_xor(a.z, off, 64); a.w += __shfl_xor(a.w, off, 64);
        b.x += __shfl_xor(b.x, off, 64); b.y += __shfl_xor(b.y, off, 64);
        b.z += __shfl_xor(b.z, off, 64); b.w += __shfl_xor(b.w, off, 64);
    }
    if ((tid & 63) == 0) { red[tid >> 6][0] = a; red[tid >> 6][1] = b; }
    __syncthreads();
    float4 sa = red[0][0], sb = red[0][1];
#pragma unroll
    for (int w = 1; w < NWAVE; ++w) { sa = f4add(sa, red[w][0]); sb = f4add(sb, red[w][1]); }
    a = sa; b = sb;   // no trailing sync
}

__device__ __forceinline__ float block_reduce1(float v, float *red, int tid) {
#pragma unroll
    for (int off = 1; off < 64; off <<= 1) v += __shfl_xor(v, off, 64);
    if ((tid & 63) == 0) red[tid >> 6] = v;
    __syncthreads();
    float s = 0.f;
#pragma unroll
    for (int w = 0; w < NWAVE; ++w) s += red[w];
    __syncthreads();
    return s;
}

__device__ __forceinline__ void redpair(float4 &a, float4 &b,
                                        float4 *redA, float4 *redB, int tid) {
#pragma unroll
    for (int off = 1; off < 64; off <<= 1) {
        a.x += __shfl_xor(a.x, off, 64); a.y += __shfl_xor(a.y, off, 64);
        a.z += __shfl_xor(a.z, off, 64); a.w += __shfl_xor(a.w, off, 64);
        b.x += __shfl_xor(b.x, off, 64); b.y += __shfl_xor(b.y, off, 64);
        b.z += __shfl_xor(b.z, off, 64); b.w += __shfl_xor(b.w, off, 64);
    }
    int w = tid >> 6;
    if ((tid & 63) == 0) { redA[w] = a; redB[w] = b; }
    __syncthreads();
    int p = w ^ 1;
    a = f4add(redA[w], redA[p]);
    b = f4add(redB[w], redB[p]);
    __syncthreads();
}

// ---------------- scan GEMV + fused-stat LN (3 syncs per layer) ---------
template <int K>
__device__ __forceinline__ void gemv_ln_scan(const float4 *__restrict__ inA,
                                             const float *__restrict__ W,
                                             const float *__restrict__ bias,
                                             const float *__restrict__ gam,
                                             const float *__restrict__ bet,
                                             float4 *__restrict__ outA,
                                             ScanS &S, int tid, int ks, int cq,
                                             int myc) {
    constexpr int kc = K / 4;
    constexpr int q4 = kc / 4;
    constexpr int seg = K / 4;
    const float4 *Wp = (const float4 *)W + (size_t)(ks * kc) * (HDIM / 4) + cq;
    const float4 *ap = inA + ks * q4;
    float4 acc0 = f4zero(), acc1 = f4zero(), acc2 = f4zero(), acc3 = f4zero();
#pragma unroll 4
    for (int q = 0; q < q4; ++q) {
        float4 a0 = ap[q];                 // LDS b128 broadcast
        float4 a1 = ap[q + seg];
        float4 a2 = ap[q + 2 * seg];
        float4 a3 = ap[q + 3 * seg];
        float4 w0 = ntload4(Wp + (size_t)(4 * q + 0) * (HDIM / 4));  // stream
        float4 w1 = ntload4(Wp + (size_t)(4 * q + 1) * (HDIM / 4));
        float4 w2 = ntload4(Wp + (size_t)(4 * q + 2) * (HDIM / 4));
        float4 w3 = ntload4(Wp + (size_t)(4 * q + 3) * (HDIM / 4));
        acc0 = f4fma(a0, w0.x, acc0); acc1 = f4fma(a0, w0.y, acc1);
        acc2 = f4fma(a0, w0.z, acc2); acc3 = f4fma(a0, w0.w, acc3);
        acc0 = f4fma(a1, w1.x, acc0); acc1 = f4fma(a1, w1.y, acc1);
        acc2 = f4fma(a1, w1.z, acc2); acc3 = f4fma(a1, w1.w, acc3);
        acc0 = f4fma(a2, w2.x, acc0); acc1 = f4fma(a2, w2.y, acc1);
        acc2 = f4fma(a2, w2.z, acc2); acc3 = f4fma(a2, w2.w, acc3);
        acc0 = f4fma(a3, w3.x, acc0); acc1 = f4fma(a3, w3.y, acc1);
        acc2 = f4fma(a3, w3.z, acc2); acc3 = f4fma(a3, w3.w, acc3);
    }
    S.part[0][ks][cq] = acc0;
    S.part[1][ks][cq] = acc1;
    S.part[2][ks][cq] = acc2;
    S.part[3][ks][cq] = acc3;
    __syncthreads();                                   // sync 1
    // combine: thread tid owns column myc = 4*cq + ks
    const int j = ks, cb = cq;
    float4 z = f4add(f4add(S.part[j][0][cb], S.part[j][1][cb]),
                     f4add(S.part[j][2][cb], S.part[j][3][cb]));
    float bc = bias[myc];
    z.x += bc; z.y += bc; z.z += bc; z.w += bc;
    // fused stats: one allreduce for (sum, sumsq); var = E[z^2] - m^2
    const float inv = 1.f / (float)HDIM;
    float4 s1 = z;
    float4 s2 = make_float4(z.x * z.x, z.y * z.y, z.z * z.z, z.w * z.w);
    allreduce2_1s(s1, s2, S.red2, tid);                // sync 2
    float4 m = f4scale(s1, inv);
    float4 e2 = f4scale(s2, inv);
    float4 var = make_float4(fmaxf(e2.x - m.x * m.x, 0.f),
                             fmaxf(e2.y - m.y * m.y, 0.f),
                             fmaxf(e2.z - m.z * m.z, 0.f),
                             fmaxf(e2.w - m.w * m.w, 0.f));
    float4 rs;
    rs.x = 1.f / sqrtf(var.x + LN_EPS);
    rs.y = 1.f / sqrtf(var.y + LN_EPS);
    rs.z = 1.f / sqrtf(var.z + LN_EPS);
    rs.w = 1.f / sqrtf(var.w + LN_EPS);
    float4 d = f4sub(z, m);
    float gc = gam[myc], ec = bet[myc];
    float4 h;
    h.x = fmaxf(fmaf(d.x * rs.x, gc, ec), 0.f);
    h.y = fmaxf(fmaf(d.y * rs.y, gc, ec), 0.f);
    h.z = fmaxf(fmaf(d.z * rs.z, gc, ec), 0.f);
    h.w = fmaxf(fmaf(d.w * rs.w, gc, ec), 0.f);
    outA[tid] = h;
    __syncthreads();                                   // sync 3
}

// ---------------- scan role: qtrunk + sampling ---------------------------
__device__ void scan_role(const Params &P, int bid, ScanS &S) {
    const int tid = threadIdx.x;
    const int ks = tid >> 7;
    const int cq = tid & 127;
    const int myc = 4 * cq + ks;
    const int row0 = bid * RPB;

    if (tid < VDIM) { S.VT[tid] = f4zero(); S.ord[tid] = P.top_order[tid]; }
    __syncthreads();
    if (tid < VDIM) {
        int nd = S.ord[tid];
        int mm = 0;
        for (int jj = 0; jj < tid; ++jj) mm |= P.pa_mask[nd * VDIM + S.ord[jj]];
        S.emptyb[tid] = (mm == 0);
        S.VPT[(tid & 3) * 32 + (tid >> 2)] = f4zero();   // V=0 -> V_pa=0
    }
    __syncthreads();

    for (int i = 0; i < VDIM; ++i) {
        const int node = S.ord[i];

        gemv_ln_scan<VDIM>(S.VPT, P.q_w1, P.q_b1, P.q_g1, P.q_be1, S.ATa, S, tid, ks, cq, myc);
        gemv_ln_scan<HDIM>(S.ATa, P.q_w2, P.q_b2, P.q_g2, P.q_be2, S.ATb, S, tid, ks, cq, myc);
        gemv_ln_scan<HDIM>(S.ATb, P.q_w3, P.q_b3, P.q_g3, P.q_be3, S.ATa, S, tid, ks, cq, myc);

        // head: x[r] = sum_c h3[r][c] * q_W[node][c]  (broadcast to all)
        float wq = P.q_W[(size_t)node * HDIM + myc];
        float4 x4 = allreduce4_1s(f4scale(S.ATa[tid], wq), S.redH, tid);

        // merged sample + VPT(i+1) phase: ONE sync
        {
            const bool empty = (S.emptyb[i] != 0);
            const float qb = P.q_bias[node];
            const float mg = P.q_marg[node];
            float a0 = empty ? mg : x4.x + qb;
            float a1 = empty ? mg : x4.y + qb;
            float a2 = empty ? mg : x4.z + qb;
            float a3 = empty ? mg : x4.w + qb;
            float4 pv = make_float4(1.f / (1.f + expf(-a0)), 1.f / (1.f + expf(-a1)),
                                    1.f / (1.f + expf(-a2)), 1.f / (1.f + expf(-a3)));
            float4 uv = *(const float4 *)(P.u + (size_t)i * BATCH + row0);
            float4 newv = make_float4(uv.x < pv.x ? 1.f : -1.f,
                                      uv.y < pv.y ? 1.f : -1.f,
                                      uv.z < pv.z ? 1.f : -1.f,
                                      uv.w < pv.w ? 1.f : -1.f);
            if (tid < VDIM) {
                float mk = 0.f;
                if (i + 1 < VDIM) {
                    int nodeN = S.ord[i + 1];
                    mk = (float)P.pa_mask[nodeN * VDIM + tid];
                }
                float4 vk = S.VT[tid];
                if (tid == node) { vk = newv; S.VT[tid] = newv; }
                S.VPT[(tid & 3) * 32 + (tid >> 2)] = f4scale(vk, mk);
            }
            if (tid < RPB) {
                float pr = f4get(pv, tid);
                float vr = f4get(newv, tid);
                __hip_atomic_store(&P.vs[(size_t)i * BATCH + row0 + tid], vr,
                                   __ATOMIC_RELAXED, __HIP_MEMORY_SCOPE_AGENT);
                P.lp[(size_t)i * BATCH + row0 + tid] =
                    (vr > 0.f) ? logf(pr) : log1pf(-pr);
            }
            __syncthreads();
            if (tid == 0)
                __hip_atomic_store(P.wflag + bid, i + 1,
                                   __ATOMIC_RELEASE, __HIP_MEMORY_SCOPE_AGENT);
        }
    }

    // terminal score: V . J . V per row
    float4 inner = f4zero();
    if (tid < VDIM) {
#pragma unroll 4
        for (int ii = 0; ii < VDIM; ++ii)
            inner = f4fma(S.VT[ii], P.J[(size_t)ii * VDIM + tid], inner);
        float4 vc = S.VT[tid];
        inner = make_float4(inner.x * vc.x, inner.y * vc.y, inner.z * vc.z, inner.w * vc.w);
    }
    float4 sc4 = allreduce4_1s(inner, S.redH, tid);
    if (tid < RPB) P.score[row0 + tid] = f4get(sc4, tid);
    if (tid < VDIM) {
        float4 v = S.VT[tid];
        P.V_out[(size_t)(row0 + 0) * VDIM + tid] = v.x;
        P.V_out[(size_t)(row0 + 1) * VDIM + tid] = v.y;
        P.V_out[(size_t)(row0 + 2) * VDIM + tid] = v.z;
        P.V_out[(size_t)(row0 + 3) * VDIM + tid] = v.w;
    }
}

// ---------------- fnet layer, 512 threads, 32-row tile -------------------
template <int K>
__device__ __forceinline__ void flayer512(const float *__restrict__ in,
                                          const float *__restrict__ W,
                                          const float *__restrict__ bias,
                                          const float *__restrict__ gam,
                                          const float *__restrict__ bet,
                                          float *__restrict__ out,
                                          float4 *redA, float4 *redB, int tid) {
    const int rh = tid >> 7;
    const int cq = tid & 127;
    const float4 *Wv = (const float4 *)W + cq;
    float4 accA[4], accB[4];
#pragma unroll
    for (int j = 0; j < 4; ++j) { accA[j] = f4zero(); accB[j] = f4zero(); }
#pragma unroll 4
    for (int k = 0; k < K; ++k) {
        float4 w = ntload4(Wv + (size_t)k * (HDIM / 4));   // stream
        const float *ip = in + k * FROWS + 8 * rh;
        float4 vA = *(const float4 *)ip;
        float4 vB = *(const float4 *)(ip + 4);
        accA[0] = f4fma(vA, w.x, accA[0]); accB[0] = f4fma(vB, w.x, accB[0]);
        accA[1] = f4fma(vA, w.y, accA[1]); accB[1] = f4fma(vB, w.y, accB[1]);
        accA[2] = f4fma(vA, w.z, accA[2]); accB[2] = f4fma(vB, w.z, accB[2]);
        accA[3] = f4fma(vA, w.w, accA[3]); accB[3] = f4fma(vB, w.w, accB[3]);
    }
    float4 b4 = ((const float4 *)bias)[cq];
    float bb[4] = {b4.x, b4.y, b4.z, b4.w};
#pragma unroll
    for (int j = 0; j < 4; ++j) {
        accA[j].x += bb[j]; accA[j].y += bb[j]; accA[j].z += bb[j]; accA[j].w += bb[j];
        accB[j].x += bb[j]; accB[j].y += bb[j]; accB[j].z += bb[j]; accB[j].w += bb[j];
    }
    const float inv = 1.f / (float)HDIM;
    float4 sA = f4add(f4add(accA[0], accA[1]), f4add(accA[2], accA[3]));
    float4 sB = f4add(f4add(accB[0], accB[1]), f4add(accB[2], accB[3]));
    redpair(sA, sB, redA, redB, tid);
    float4 mA = f4scale(sA, inv), mB = f4scale(sB, inv);
    float4 dA[4], dB[4];
    float4 qA = f4zero(), qB = f4zero();
#pragma unroll
    for (int j = 0; j < 4; ++j) {
        dA[j] = f4sub(accA[j], mA);
        dB[j] = f4sub(accB[j], mB);
        qA.x += dA[j].x * dA[j].x; qA.y += dA[j].y * dA[j].y;
        qA.z += dA[j].z * dA[j].z; qA.w += dA[j].w * dA[j].w;
        qB.x += dB[j].x * dB[j].x; qB.y += dB[j].y * dB[j].y;
        qB.z += dB[j].z * dB[j].z; qB.w += dB[j].w * dB[j].w;
    }
    redpair(qA, qB, redA, redB, tid);
    float4 rsA, rsB;
    rsA.x = 1.f / sqrtf(qA.x * inv + LN_EPS); rsA.y = 1.f / sqrtf(qA.y * inv + LN_EPS);
    rsA.z = 1.f / sqrtf(qA.z * inv + LN_EPS); rsA.w = 1.f / sqrtf(qA.w * inv + LN_EPS);
    rsB.x = 1.f / sqrtf(qB.x * inv + LN_EPS); rsB.y = 1.f / sqrtf(qB.y * inv + LN_EPS);
    rsB.z = 1.f / sqrtf(qB.z * inv + LN_EPS); rsB.w = 1.f / sqrtf(qB.w * inv + LN_EPS);
    float4 g4 = ((const float4 *)gam)[cq];
    float4 e4 = ((const float4 *)bet)[cq];
    float gg[4] = {g4.x, g4.y, g4.z, g4.w};
    float ee[4] = {e4.x, e4.y, e4.z, e4.w};
#pragma unroll
    for (int j = 0; j < 4; ++j) {
        float4 hA, hB;
        hA.x = fmaxf(fmaf(dA[j].x * rsA.x, gg[j], ee[j]), 0.f);
        hA.y = fmaxf(fmaf(dA[j].y * rsA.y, gg[j], ee[j]), 0.f);
        hA.z = fmaxf(fmaf(dA[j].z * rsA.z, gg[j], ee[j]), 0.f);
        hA.w = fmaxf(fmaf(dA[j].w * rsA.w, gg[j], ee[j]), 0.f);
        hB.x = fmaxf(fmaf(dB[j].x * rsB.x, gg[j], ee[j]), 0.f);
        hB.y = fmaxf(fmaf(dB[j].y * rsB.y, gg[j], ee[j]), 0.f);
        hB.z = fmaxf(fmaf(dB[j].z * rsB.z, gg[j], ee[j]), 0.f);
        hB.w = fmaxf(fmaf(dB[j].w * rsB.w, gg[j], ee[j]), 0.f);
        float *op = out + (4 * cq + j) * FROWS + 8 * rh;
        *(float4 *)op = hA;
        *(float4 *)(op + 4) = hB;
    }
    __syncthreads();
}

// ---------------- worker role --------------------------------------------
__device__ void worker_role(const Params &P, int wid, WorkS &S) {
    const int tid = threadIdx.x;
    if (tid < VDIM) S.ord[tid] = P.top_order[tid];
    __syncthreads();
    if (tid < VDIM) S.invp[S.ord[tid]] = tid;
    __syncthreads();
    const int g = wid & (NGRP - 1);
    const int r0 = g * FROWS;

    for (int tile = wid; tile < VDIM * NGRP; tile += NWORK) {
        const int t = tile >> 4;
        if (t == VDIM - 1) continue;
        if (tid < SBPG) {
            const int need = t + 1;
            while (__hip_atomic_load(P.wflag + (SBPG * g + tid),
                                     __ATOMIC_RELAXED,
                                     __HIP_MEMORY_SCOPE_AGENT) < need)
                __builtin_amdgcn_s_sleep(4);
        }
        __syncthreads();
        for (int idx = tid; idx < VDIM * FROWS; idx += NT) {
            int k = idx >> 5, rr = idx & (FROWS - 1);
            int s = S.invp[k];
            S.Vt[idx] = (s <= t)
                ? __hip_atomic_load(&P.vs[(size_t)s * BATCH + r0 + rr],
                                    __ATOMIC_RELAXED, __HIP_MEMORY_SCOPE_AGENT)
                : 0.f;
        }
        __syncthreads();

        flayer512<VDIM>(S.Vt, P.f_w1, P.f_b1, P.f_g1, P.f_be1, S.A, S.redA, S.redB, tid);
        flayer512<HDIM>(S.A, P.f_w2, P.f_b2, P.f_g2, P.f_be2, S.A, S.redA, S.redB, tid);
        flayer512<HDIM>(S.A, P.f_w3, P.f_b3, P.f_g3, P.f_be3, S.A, S.redA, S.redB, tid);

        const int rh = tid >> 7, cq = tid & 127;
        float4 w4 = ((const float4 *)P.f_w4)[cq];
        float ww[4] = {w4.x, w4.y, w4.z, w4.w};
        float4 sA = f4zero(), sB = f4zero();
#pragma unroll
        for (int j = 0; j < 4; ++j) {
            const float *ap2 = S.A + (4 * cq + j) * FROWS + 8 * rh;
            float4 vA = *(const float4 *)ap2;
            float4 vB = *(const float4 *)(ap2 + 4);
            sA = f4fma(vA, ww[j], sA);
            sB = f4fma(vB, ww[j], sB);
        }
        redpair(sA, sB, S.redA, S.redB, tid);
        if (cq == 0) {
            float b4v = P.f_b4[0];
            float *dst = P.lf + (size_t)t * BATCH + r0 + 8 * rh;
            dst[0] = sA.x + b4v; dst[1] = sA.y + b4v;
            dst[2] = sA.z + b4v; dst[3] = sA.w + b4v;
            dst[4] = sB.x + b4v; dst[5] = sB.y + b4v;
            dst[6] = sB.z + b4v; dst[7] = sB.w + b4v;
        }
        __syncthreads();
    }
}

// XCD-partitioned roles (perf heuristic only; correctness mapping-free):
// scan -> XCDs 0-3 (q-weights resident), workers -> XCDs 4-7 (f-weights).
__global__ __launch_bounds__(NT) void gfn_main(Params P) {
    __shared__ SMem sm;
    const int xcd = blockIdx.x & 7;
    const int grp = blockIdx.x >> 3;
    if (xcd < 4) scan_role(P, grp * 4 + xcd, sm.s);
    else         worker_role(P, grp * 4 + (xcd - 4), sm.w);
}

// ---------------- loss ----------------
__global__ __launch_bounds__(NT) void gfn_loss(Params P) {
    __shared__ float H1[HDIM], H2[HDIM];
    __shared__ float red1[NWAVE];
    const int tid = threadIdx.x;
    const float inv = 1.f / (float)HDIM;

    float z = P.f_b1[tid];
    float m = block_reduce1(z, red1, tid) * inv;
    float d = z - m;
    float var = block_reduce1(d * d, red1, tid) * inv;
    float h = fmaxf(fmaf(d * (1.f / sqrtf(var + LN_EPS)), P.f_g1[tid], P.f_be1[tid]), 0.f);
    H1[tid] = h;
    __syncthreads();

    float acc = 0.f;
    for (int k = 0; k < HDIM; ++k) acc = fmaf(H1[k], P.f_w2[(size_t)k * HDIM + tid], acc);
    z = acc + P.f_b2[tid];
    m = block_reduce1(z, red1, tid) * inv;
    d = z - m;
    var = block_reduce1(d * d, red1, tid) * inv;
    h = fmaxf(fmaf(d * (1.f / sqrtf(var + LN_EPS)), P.f_g2[tid], P.f_be2[tid]), 0.f);
    H2[tid] = h;
    __syncthreads();

    acc = 0.f;
    for (int k = 0; k < HDIM; ++k) acc = fmaf(H2[k], P.f_w3[(size_t)k * HDIM + tid], acc);
    z = acc + P.f_b3[tid];
    m = block_reduce1(z, red1, tid) * inv;
    d = z - m;
    var = block_reduce1(d * d, red1, tid) * inv;
    h = fmaxf(fmaf(d * (1.f / sqrtf(var + LN_EPS)), P.f_g3[tid], P.f_be3[tid]), 0.f);
    float F0 = block_reduce1(h * P.f_w4[tid], red1, tid) + P.f_b4[0];

    const int b = tid;
    float lfp = F0;
    float s = 0.f;
    for (int t = 0; t < VDIM; ++t) {
        float lp = P.lp[(size_t)t * BATCH + b];
        float lfn = (t == VDIM - 1) ? P.score[b] : P.lf[(size_t)t * BATCH + b];
        float dd = lfp + lp - lfn;
        s = fmaf(dd, dd, s);
        lfp = lfn;
    }
    s *= (1.f / (float)VDIM);
    float total = block_reduce1(s, red1, tid) * (1.f / (float)BATCH);
    if (tid == 0) P.loss[0] = total;
}

extern "C" void kernel_launch(void *const *d_in, const int *in_sizes, int n_in,
                              void *d_out, int out_size, void *d_ws, size_t ws_size,
                              hipStream_t stream) {
    Params P;
    P.u     = (const float *)d_in[0];
    P.q_w1  = (const float *)d_in[1];
    P.q_b1  = (const float *)d_in[2];
    P.q_g1  = (const float *)d_in[3];
    P.q_be1 = (const float *)d_in[4];
    P.q_w2  = (const float *)d_in[5];
    P.q_b2  = (const float *)d_in[6];
    P.q_g2  = (const float *)d_in[7];
    P.q_be2 = (const float *)d_in[8];
    P.q_w3  = (const float *)d_in[9];
    P.q_b3  = (const float *)d_in[10];
    P.q_g3  = (const float *)d_in[11];
    P.q_be3 = (const float *)d_in[12];
    P.q_W   = (const float *)d_in[13];
    P.q_bias= (const float *)d_in[14];
    P.q_marg= (const float *)d_in[15];
    P.f_w1  = (const float *)d_in[16];
    P.f_b1  = (const float *)d_in[17];
    P.f_g1  = (const float *)d_in[18];
    P.f_be1 = (const float *)d_in[19];
    P.f_w2  = (const float *)d_in[20];
    P.f_b2  = (const float *)d_in[21];
    P.f_g2  = (const float *)d_in[22];
    P.f_be2 = (const float *)d_in[23];
    P.f_w3  = (const float *)d_in[24];
    P.f_b3  = (const float *)d_in[25];
    P.f_g3  = (const float *)d_in[26];
    P.f_be3 = (const float *)d_in[27];
    P.f_w4  = (const float *)d_in[28];
    P.f_b4  = (const float *)d_in[29];
    P.J     = (const float *)d_in[30];
    P.top_order = (const int *)d_in[31];
    P.pa_mask   = (const int *)d_in[32];

    float *ws = (float *)d_ws;
    P.V_out = (float *)d_out;
    P.loss  = (float *)d_out + (size_t)BATCH * VDIM;
    P.lp    = ws;                                       // [128][512]
    P.lf    = ws + (size_t)VDIM * BATCH;                // [128][512]
    P.score = ws + 2 * (size_t)VDIM * BATCH;            // [512]
    P.vs    = ws + 2 * (size_t)VDIM * BATCH + BATCH;    // [128][512]
    P.wflag = (int *)(ws + 3 * (size_t)VDIM * BATCH + BATCH);  // [128]

    hipMemsetAsync(P.wflag, 0, NBLK * sizeof(int), stream);
    gfn_main<<<dim3(NBLK + NWORK), dim3(NT), 0, stream>>>(P);
    gfn_loss<<<dim3(1), dim3(NT), 0, stream>>>(P);
}